// Round 8
// baseline (596.877 us; speedup 1.0000x reference)
//
#include <hip/hip_runtime.h>
#include <math.h>

#define LR 0.05f

typedef __attribute__((ext_vector_type(8))) short short8;
typedef __attribute__((ext_vector_type(4))) float f32x4;

#define MFMA16(a, b, c) __builtin_amdgcn_mfma_f32_16x16x32_bf16(a, b, c, 0, 0, 0)

__device__ __forceinline__ unsigned short f2bf(float v) {
  unsigned int u = __float_as_uint(v);
  u += 0x7fffu + ((u >> 16) & 1u);
  return (unsigned short)(u >> 16);
}

__device__ __forceinline__ void ce2(float& a, float& b, bool asc) {
  float lo = fminf(a, b), hi = fmaxf(a, b);
  a = asc ? lo : hi; b = asc ? hi : lo;
}

// 8-elem/lane wave-local bitonic helpers (512 elements in one wave)
__device__ __forceinline__ void sort8_intra(float* v, int ebase, int k, int j) {
  #pragma unroll
  for (int m = 0; m < 8; ++m) {
    if ((m & j) == 0) {
      bool asc = (((ebase + m) & k) == 0);
      ce2(v[m], v[m | j], asc);
    }
  }
}
__device__ __forceinline__ void sort8_shuf(float* v, int ebase, int k, int j) {
  int lm = j >> 3;
  bool amLow = ((ebase & j) == 0);
  bool asc = ((ebase & k) == 0);
  bool keepMin = (amLow == asc);
  #pragma unroll
  for (int m = 0; m < 8; ++m) {
    float pv = __shfl_xor(v[m], lm);
    v[m] = keepMin ? fminf(v[m], pv) : fmaxf(v[m], pv);
  }
}

// ---------------- prep: build bf16 weight copies -----------------------------
__global__ __launch_bounds__(256) void prep_kernel(
    const float* __restrict__ W1a, const float* __restrict__ W1b,
    const float* __restrict__ W2a, const float* __restrict__ W2b,
    unsigned short* __restrict__ W2bfA, unsigned short* __restrict__ W2bfB,
    unsigned short* __restrict__ W2TbfA, unsigned short* __restrict__ W2TbfB,
    unsigned short* __restrict__ W1TbfA, unsigned short* __restrict__ W1TbfB,
    unsigned short* __restrict__ W1tailA, unsigned short* __restrict__ W1tailB)
{
  int i = blockIdx.x * 256 + threadIdx.x;
  if (i < 131072) {
    const float* W2 = (i >> 16) ? W2b : W2a;
    unsigned short* o = (i >> 16) ? W2bfB : W2bfA;
    int j = i & 65535;
    o[j] = f2bf(W2[j]);
  } else if (i < 262144) {
    int i2 = i - 131072;
    const float* W2 = (i2 >> 16) ? W2b : W2a;
    unsigned short* o = (i2 >> 16) ? W2TbfB : W2TbfA;
    int j = i2 & 65535;
    int n = j >> 8, k = j & 255;
    o[j] = f2bf(W2[k * 256 + n]);
  } else if (i < 278528) {
    int i2 = i - 262144;
    const float* W1 = (i2 >> 13) ? W1b : W1a;
    unsigned short* o = (i2 >> 13) ? W1TbfB : W1TbfA;
    int j = i2 & 8191;
    int n = j >> 5, k = j & 31;
    o[j] = (k < 23) ? f2bf(W1[k * 256 + n]) : (unsigned short)0;
  } else if (i < 286720) {
    int i2 = i - 278528;
    const float* W1 = (i2 >> 12) ? W1b : W1a;
    unsigned short* o = (i2 >> 12) ? W1tailB : W1tailA;
    int j = i2 & 4095;
    int d = j >> 8, tt = j & 255;
    o[j] = (d < 6) ? f2bf(W1[(17 + d) * 256 + tt]) : (unsigned short)0;
  }
}

// ---------------- fused: 5 x (score + SVGD) + epilogue, TWO batches per block
// 512 threads / 8 waves; waves 0-3 own batch 2b (rows 0-31), waves 4-7 own
// batch 2b+1 (rows 32-63). Per-wave inner loops identical to the 256-thread
// version (same VGPR demand ~112), but each barrier covers 2 batches (half
// the barrier overhead per batch), LDS ~78 KB -> exactly 2 blocks/CU =
// 16 waves/CU, and grid 512 = one clean residency round (no 1/3-occupancy
// tail round like 1024 blocks / 768 slots had).
__global__ __launch_bounds__(512) void fused_kernel(
    const float* __restrict__ obs, const float* __restrict__ a0,
    const float* __restrict__ b1a, const float* __restrict__ b2a,
    const float* __restrict__ W3a, const float* __restrict__ b3a,
    const float* __restrict__ b1b, const float* __restrict__ b2b,
    const float* __restrict__ W3b, const float* __restrict__ b3b,
    const unsigned short* __restrict__ W2bfA, const unsigned short* __restrict__ W2bfB,
    const unsigned short* __restrict__ W2TbfA, const unsigned short* __restrict__ W2TbfB,
    const unsigned short* __restrict__ W1TbfA, const unsigned short* __restrict__ W1TbfB,
    const unsigned short* __restrict__ W1tailA, const unsigned short* __restrict__ W1tailB,
    float* __restrict__ out)
{
  __shared__ __align__(16) unsigned short buf0[64][264];  // h1a/dh2a/dh1a_m; d2s aliases
  __shared__ __align__(16) unsigned short buf1[64][264];  // h1b/dh2b/dh1b_m
  __shared__ __align__(16) unsigned short xsm[64][40];    // bf16 x (obs cols persist)
  __shared__ __align__(16) float upool[768];              // qpart[2][8][32] | redS[128][6]
  __shared__ float acur[64][6];
  __shared__ float Svv[64][6];
  __shared__ float XSsh[64];
  __shared__ float logps[64];
  __shared__ float asq[64];
  __shared__ int   selsh[64];
  __shared__ float medsh[2][2];

  float (*qpart)[8][32] = (float (*)[8][32])upool;
  float (*redS)[6] = (float (*)[6])upool;

  const int t = threadIdx.x;
  const int lane = t & 63, wv = t >> 6, quad = lane >> 4, l16 = lane & 15;
  const int h = wv >> 2;          // batch half (0/1)
  const int hr = h * 32;          // row base of my half
  const int ctb = (wv & 3) * 4;   // my 4 col-tiles
  const int b = blockIdx.x;
  const int base64 = b * 64;
  const long abase = (long)b * 384;

  // per-half d2 scratch aliased into buf0 (each half: 1024 floats = 4 KB,
  // well inside its 32x264x2 = 16.9 KB row range)
  float* d2s0 = (float*)&buf0[0][0];
  float* d2s1 = (float*)&buf0[32][0];

  // ---- init ----
  if (t < 384) { int r = t / 6, d = t - r * 6; acur[r][d] = a0[abase + t]; }
  if (t < 64) {
    float s = 0.f;
    #pragma unroll
    for (int d = 0; d < 6; ++d) { float x0 = a0[abase + t * 6 + d]; s += x0 * x0; }
    asq[t] = s; logps[t] = 0.f;
  }
  for (int idx = t; idx < 64 * 40; idx += 512) {
    int r = idx / 40, k = idx - r * 40;
    float v = 0.f;
    if (k < 17) v = obs[(base64 + r) * 17 + k];
    else if (k < 23) v = a0[abase + r * 6 + (k - 17)];
    xsm[r][k] = f2bf(v);
  }
  __syncthreads();

  #pragma unroll 1
  for (int s = 0; s < 5; ++s) {
    if (s > 0) {
      if (t < 384) { int r = t / 6, d = t - r * 6; xsm[r][17 + d] = f2bf(acur[r][d]); }
      __syncthreads();
    }

    // ================= score (both halves in parallel) =================
    unsigned int m1a_bits = 0, m1b_bits = 0, m2a_bits = 0, m2b_bits = 0;

    #pragma unroll 1
    for (int net = 0; net < 2; ++net) {
      const unsigned short* W1T = net ? W1TbfB : W1TbfA;
      const unsigned short* W2T = net ? W2TbfB : W2TbfA;
      const float* b1 = net ? b1b : b1a;
      const float* b2 = net ? b2b : b2a;
      const float* W3 = net ? W3b : W3a;
      unsigned short (*hbuf)[264] = net ? buf1 : buf0;

      // h1 = relu(x @ W1 + b1); lane records its own mask bits (C-layout)
      unsigned int m1 = 0;
      {
        short8 ax0 = *(const short8*)&xsm[hr + l16][quad * 8];
        short8 ax1 = *(const short8*)&xsm[hr + 16 + l16][quad * 8];
        #pragma unroll
        for (int c = 0; c < 4; ++c) {
          int col = (ctb + c) * 16 + l16;
          short8 bw = *(const short8*)&W1T[col * 32 + quad * 8];
          f32x4 z = {0.f, 0.f, 0.f, 0.f};
          f32x4 h0 = MFMA16(ax0, bw, z);
          f32x4 h1v = MFMA16(ax1, bw, z);
          float b1v = b1[col];
          #pragma unroll
          for (int g = 0; g < 4; ++g) {
            float v0 = h0[g] + b1v;
            float v1 = h1v[g] + b1v;
            if (v0 > 0.f) m1 |= 1u << ((0 * 4 + c) * 4 + g);
            if (v1 > 0.f) m1 |= 1u << ((1 * 4 + c) * 4 + g);
            hbuf[hr + quad * 4 + g][col] = (v0 > 0.f) ? f2bf(v0) : (unsigned short)0;
            hbuf[hr + 16 + quad * 4 + g][col] = (v1 > 0.f) ? f2bf(v1) : (unsigned short)0;
          }
        }
      }
      if (net) m1b_bits = m1; else m1a_bits = m1;
      __syncthreads();

      // h2pre = h1 @ W2 — depth-2 prefetched K-loop
      f32x4 acc[2][4];
      #pragma unroll
      for (int rt = 0; rt < 2; ++rt)
        #pragma unroll
        for (int c = 0; c < 4; ++c) acc[rt][c] = (f32x4){0.f, 0.f, 0.f, 0.f};
      {
        short8 bwp[4];
        #pragma unroll
        for (int c = 0; c < 4; ++c)
          bwp[c] = *(const short8*)&W2T[((ctb + c) * 16 + l16) * 256 + quad * 8];
        #pragma unroll 1
        for (int k = 0; k < 8; ++k) {
          short8 bwc[4];
          #pragma unroll
          for (int c = 0; c < 4; ++c) bwc[c] = bwp[c];
          if (k < 7) {
            #pragma unroll
            for (int c = 0; c < 4; ++c)
              bwp[c] = *(const short8*)&W2T[((ctb + c) * 16 + l16) * 256 + (k + 1) * 32 + quad * 8];
          }
          short8 a0f = *(const short8*)&hbuf[hr + l16][k * 32 + quad * 8];
          short8 a1f = *(const short8*)&hbuf[hr + 16 + l16][k * 32 + quad * 8];
          #pragma unroll
          for (int c = 0; c < 4; ++c) {
            acc[0][c] = MFMA16(a0f, bwc[c], acc[0][c]);
            acc[1][c] = MFMA16(a1f, bwc[c], acc[1][c]);
          }
        }
      }

      // bias+relu, q partials, m2 bits
      float pq[2][4] = {{0.f, 0.f, 0.f, 0.f}, {0.f, 0.f, 0.f, 0.f}};
      unsigned int m2 = 0;
      #pragma unroll
      for (int rt = 0; rt < 2; ++rt)
        #pragma unroll
        for (int c = 0; c < 4; ++c) {
          int col = (ctb + c) * 16 + l16;
          float b2v = b2[col], w3v = W3[col];
          #pragma unroll
          for (int g = 0; g < 4; ++g) {
            float v = acc[rt][c][g] + b2v;
            if (v > 0.f) {
              m2 |= 1u << ((rt * 4 + c) * 4 + g);
              pq[rt][g] += v * w3v;
            }
          }
        }
      if (net) m2b_bits = m2; else m2a_bits = m2;
      #pragma unroll
      for (int off = 8; off; off >>= 1) {
        #pragma unroll
        for (int rt = 0; rt < 2; ++rt)
          #pragma unroll
          for (int g = 0; g < 4; ++g)
            pq[rt][g] += __shfl_xor(pq[rt][g], off, 16);
      }
      if (l16 == 0) {
        #pragma unroll
        for (int rt = 0; rt < 2; ++rt)
          #pragma unroll
          for (int g = 0; g < 4; ++g)
            qpart[net][wv][rt * 16 + quad * 4 + g] = pq[rt][g];
      }
      __syncthreads();
    }

    // q assembly + min-selection (64 rows across both halves)
    if (t < 64) {
      int hh = t >> 5, i = t & 31;
      float qa = b3a[0], qb = b3b[0];
      #pragma unroll
      for (int w = 0; w < 4; ++w) {
        qa += qpart[0][hh * 4 + w][i];
        qb += qpart[1][hh * 4 + w][i];
      }
      selsh[t] = (qa <= qb) ? 0 : 1;
    }
    __syncthreads();

    // dh2 (split per net, zero-masked)
    #pragma unroll
    for (int rt = 0; rt < 2; ++rt)
      #pragma unroll
      for (int c = 0; c < 4; ++c) {
        int col = (ctb + c) * 16 + l16;
        unsigned short w3abf = f2bf(W3a[col]);
        unsigned short w3bbf = f2bf(W3b[col]);
        #pragma unroll
        for (int g = 0; g < 4; ++g) {
          int row = hr + rt * 16 + quad * 4 + g;
          int sl = selsh[row];
          int bit = (rt * 4 + c) * 4 + g;
          buf0[row][col] = (sl == 0 && ((m2a_bits >> bit) & 1)) ? w3abf : (unsigned short)0;
          buf1[row][col] = (sl == 1 && ((m2b_bits >> bit) & 1)) ? w3bbf : (unsigned short)0;
        }
      }
    __syncthreads();

    // dh1pre = dh2a @ W2a^T + dh2b @ W2b^T — two per-net prefetched passes
    f32x4 bacc[2][4];
    #pragma unroll
    for (int rt = 0; rt < 2; ++rt)
      #pragma unroll
      for (int c = 0; c < 4; ++c) bacc[rt][c] = (f32x4){0.f, 0.f, 0.f, 0.f};
    #pragma unroll 1
    for (int net = 0; net < 2; ++net) {
      const unsigned short* W2bf = net ? W2bfB : W2bfA;
      unsigned short (*db)[264] = net ? buf1 : buf0;
      short8 bwp[4];
      #pragma unroll
      for (int c = 0; c < 4; ++c)
        bwp[c] = *(const short8*)&W2bf[((ctb + c) * 16 + l16) * 256 + quad * 8];
      #pragma unroll 1
      for (int k = 0; k < 8; ++k) {
        short8 bwc[4];
        #pragma unroll
        for (int c = 0; c < 4; ++c) bwc[c] = bwp[c];
        if (k < 7) {
          #pragma unroll
          for (int c = 0; c < 4; ++c)
            bwp[c] = *(const short8*)&W2bf[((ctb + c) * 16 + l16) * 256 + (k + 1) * 32 + quad * 8];
        }
        short8 a0d = *(const short8*)&db[hr + l16][k * 32 + quad * 8];
        short8 a1d = *(const short8*)&db[hr + 16 + l16][k * 32 + quad * 8];
        #pragma unroll
        for (int c = 0; c < 4; ++c) {
          bacc[0][c] = MFMA16(a0d, bwc[c], bacc[0][c]);
          bacc[1][c] = MFMA16(a1d, bwc[c], bacc[1][c]);
        }
      }
    }
    __syncthreads();  // A reads done before masked overwrite

    // dh1: mask by m1[sel] (same lane owns same cells as in h1), split per net
    #pragma unroll
    for (int rt = 0; rt < 2; ++rt)
      #pragma unroll
      for (int c = 0; c < 4; ++c) {
        int col = (ctb + c) * 16 + l16;
        #pragma unroll
        for (int g = 0; g < 4; ++g) {
          int row = hr + rt * 16 + quad * 4 + g;
          int sl = selsh[row];
          int bit = (rt * 4 + c) * 4 + g;
          unsigned short bv = f2bf(bacc[rt][c][g]);
          buf0[row][col] = (sl == 0 && ((m1a_bits >> bit) & 1)) ? bv : (unsigned short)0;
          buf1[row][col] = (sl == 1 && ((m1b_bits >> bit) & 1)) ? bv : (unsigned short)0;
        }
      }
    __syncthreads();

    // S = dh1a_m @ W1a[17:23]^T + dh1b_m @ W1b[17:23]^T (per-half, 4 waves)
    {
      int net = (wv >> 1) & 1, rt = wv & 1;
      const unsigned short* Wt = net ? W1tailB : W1tailA;
      unsigned short (*db)[264] = net ? buf1 : buf0;
      f32x4 sacc = {0.f, 0.f, 0.f, 0.f};
      short8 bp = *(const short8*)&Wt[l16 * 256 + quad * 8];
      #pragma unroll 1
      for (int k = 0; k < 8; ++k) {
        short8 bb = bp;
        if (k < 7) bp = *(const short8*)&Wt[l16 * 256 + (k + 1) * 32 + quad * 8];
        short8 a = *(const short8*)&db[hr + rt * 16 + l16][k * 32 + quad * 8];
        sacc = MFMA16(a, bb, sacc);
      }
      if (l16 < 6) {
        #pragma unroll
        for (int g = 0; g < 4; ++g)
          redS[h * 64 + net * 32 + rt * 16 + quad * 4 + g][l16] = sacc[g];
      }
    }
    __syncthreads();

    // ================= SVGD (both halves independently) =================
    if (t < 384) {
      int r = t / 6, d = t - r * 6;
      int hh = r >> 5, i = r & 31;
      Svv[r][d] = redS[hh * 64 + i][d] + redS[hh * 64 + 32 + i][d];
    }
    for (int idx = t; idx < 2048; idx += 512) {
      int hh = idx >> 10, rem = idx & 1023;
      int i = rem >> 5, j = rem & 31;
      float sd = 0.f;
      #pragma unroll
      for (int d = 0; d < 6; ++d) {
        float df = acur[hh * 32 + i][d] - acur[hh * 32 + j][d];
        sd += df * df;
      }
      (hh ? d2s1 : d2s0)[rem] = sd;
    }
    if (t < 64) {
      float sx = 0.f;
      #pragma unroll
      for (int d = 0; d < 6; ++d) sx += acur[t][d] * Svv[t][d];
      XSsh[t] = sx;
    }
    __syncthreads();

    // exact median per half: one wave sorts the 496 unique pair distances
    // (pad to 512). full 1024 = 32 diag zeros + each pair twice ->
    // median = (p239+p240)/2 of sorted pairs.
    if ((wv & 3) == 0) {
      const float* dd = h ? d2s1 : d2s0;
      const int ebase = lane * 8;
      float v[8];
      #pragma unroll
      for (int m = 0; m < 8; ++m) {
        int idx = ebase + m;
        float val = 3.4e38f;
        if (idx < 496) {
          int i = (int)floorf(31.5f - sqrtf(992.25f - 2.0f * (float)idx));
          int Ci = 31 * i - ((i * (i - 1)) >> 1);
          int j = i + 1 + (idx - Ci);
          val = dd[i * 32 + j];
        }
        v[m] = val;
      }
      for (int k = 2; k <= 512; k <<= 1) {
        for (int j = k >> 1; j >= 8; j >>= 1) sort8_shuf(v, ebase, k, j);
        if (k >= 8) sort8_intra(v, ebase, k, 4);
        if (k >= 4) sort8_intra(v, ebase, k, 2);
        sort8_intra(v, ebase, k, 1);
      }
      #pragma unroll
      for (int m = 0; m < 8; ++m) {
        int e = ebase + m;
        if (e == 239) medsh[h][0] = v[m];
        if (e == 240) medsh[h][1] = v[m];
      }
    }
    __syncthreads();

    // K row-sums: row = t>>3 (0..63), 8 lanes per row
    const int i63 = t >> 3, l = t & 7;
    const int hh = i63 >> 5, i = i63 & 31;
    const float* dd = hh ? d2s1 : d2s0;
    float med = 0.5f * (medsh[hh][0] + medsh[hh][1]);
    float g = 1.0f / (2.0f * (med / logf(33.0f)) + 1e-8f);
    float ks0=0,ks1=0,ks2=0,ks3=0,ks4=0,ks5=0;
    float kx0=0,kx1=0,kx2=0,kx3=0,kx4=0,kx5=0;
    float krow=0.f, kd2=0.f, kxs=0.f;
    #pragma unroll
    for (int jj = 0; jj < 4; ++jj) {
      int j = l + 8 * jj;
      int rj = hh * 32 + j;
      float dv = dd[i * 32 + j];
      float kv = expf(-g * dv);
      krow += kv; kd2 += kv * dv; kxs += kv * XSsh[rj];
      ks0 += kv * Svv[rj][0]; kx0 += kv * acur[rj][0];
      ks1 += kv * Svv[rj][1]; kx1 += kv * acur[rj][1];
      ks2 += kv * Svv[rj][2]; kx2 += kv * acur[rj][2];
      ks3 += kv * Svv[rj][3]; kx3 += kv * acur[rj][3];
      ks4 += kv * Svv[rj][4]; kx4 += kv * acur[rj][4];
      ks5 += kv * Svv[rj][5]; kx5 += kv * acur[rj][5];
    }
    #pragma unroll
    for (int off = 4; off > 0; off >>= 1) {
      krow += __shfl_down(krow, off, 8);
      kd2  += __shfl_down(kd2,  off, 8);
      kxs  += __shfl_down(kxs,  off, 8);
      ks0 += __shfl_down(ks0, off, 8); kx0 += __shfl_down(kx0, off, 8);
      ks1 += __shfl_down(ks1, off, 8); kx1 += __shfl_down(kx1, off, 8);
      ks2 += __shfl_down(ks2, off, 8); kx2 += __shfl_down(kx2, off, 8);
      ks3 += __shfl_down(ks3, off, 8); kx3 += __shfl_down(kx3, off, 8);
      ks4 += __shfl_down(ks4, off, 8); kx4 += __shfl_down(kx4, off, 8);
      ks5 += __shfl_down(ks5, off, 8); kx5 += __shfl_down(kx5, off, 8);
    }
    float an0=0,an1=0,an2=0,an3=0,an4=0,an5=0, lpnew=0;
    if (l == 0) {
      const float inv_n = 1.0f / 32.0f;
      float t1sum = 0.f, p;
      p = (ks0 + 2.f*g*(acur[i63][0]*krow - kx0)) * inv_n; an0 = acur[i63][0] + LR * p; t1sum += acur[i63][0] * ks0;
      p = (ks1 + 2.f*g*(acur[i63][1]*krow - kx1)) * inv_n; an1 = acur[i63][1] + LR * p; t1sum += acur[i63][1] * ks1;
      p = (ks2 + 2.f*g*(acur[i63][2]*krow - kx2)) * inv_n; an2 = acur[i63][2] + LR * p; t1sum += acur[i63][2] * ks2;
      p = (ks3 + 2.f*g*(acur[i63][3]*krow - kx3)) * inv_n; an3 = acur[i63][3] + LR * p; t1sum += acur[i63][3] * ks3;
      p = (ks4 + 2.f*g*(acur[i63][4]*krow - kx4)) * inv_n; an4 = acur[i63][4] + LR * p; t1sum += acur[i63][4] * ks4;
      p = (ks5 + 2.f*g*(acur[i63][5]*krow - kx5)) * inv_n; an5 = acur[i63][5] + LR * p; t1sum += acur[i63][5] * ks5;
      float term1 = (-2.f * g / 31.f) * (t1sum - kxs);
      float term2 = (-2.f * g / 31.f) * (2.f * g * kd2 - 6.f * (krow - 1.f));
      lpnew = logps[i63] - LR * (term1 + term2);
    }
    __syncthreads();
    if (l == 0) {
      acur[i63][0] = an0; acur[i63][1] = an1; acur[i63][2] = an2;
      acur[i63][3] = an3; acur[i63][4] = an4; acur[i63][5] = an5;
      logps[i63] = lpnew;
    }
    __syncthreads();
  }

  // ================= epilogue =================
  if (t < 384) { int r = t / 6, d = t - r * 6; out[abase + t] = tanhf(acur[r][d]); }
  if (t < 64) {
    float st = 0.f;
    #pragma unroll
    for (int d = 0; d < 6; ++d) {
      float x = acur[t][d];
      float z = -2.f * x;
      float sp = fmaxf(z, 0.f) + log1pf(expf(-fabsf(z)));
      st += 2.f * (0.69314718056f - x - sp);
    }
    float lpn = -3.0f * logf(1.88495559215f) - (0.5f / 0.3f) * asq[t];
    XSsh[t] = lpn + logps[t] - st;
  }
  __syncthreads();
  if (t < 2) {
    float s = 0.f;
    #pragma unroll
    for (int n = 0; n < 32; ++n) s += XSsh[t * 32 + n];
    out[196608 + 2 * b + t] = s * (1.0f / 32.0f);
  }
}

extern "C" void kernel_launch(void* const* d_in, const int* in_sizes, int n_in,
                              void* d_out, int out_size, void* d_ws, size_t ws_size,
                              hipStream_t stream) {
  const float* obs  = (const float*)d_in[0];
  const float* a0   = (const float*)d_in[1];
  const float* q1W1 = (const float*)d_in[2];
  const float* q1b1 = (const float*)d_in[3];
  const float* q1W2 = (const float*)d_in[4];
  const float* q1b2 = (const float*)d_in[5];
  const float* q1W3 = (const float*)d_in[6];
  const float* q1b3 = (const float*)d_in[7];
  const float* q2W1 = (const float*)d_in[8];
  const float* q2b1 = (const float*)d_in[9];
  const float* q2W2 = (const float*)d_in[10];
  const float* q2b2 = (const float*)d_in[11];
  const float* q2W3 = (const float*)d_in[12];
  const float* q2b3 = (const float*)d_in[13];

  unsigned short* wsu = (unsigned short*)d_ws;
  unsigned short* W2bfA  = wsu;
  unsigned short* W2bfB  = W2bfA + 65536;
  unsigned short* W2TbfA = W2bfB + 65536;
  unsigned short* W2TbfB = W2TbfA + 65536;
  unsigned short* W1TbfA = W2TbfB + 65536;
  unsigned short* W1TbfB = W1TbfA + 8192;
  unsigned short* W1tailA = W1TbfB + 8192;
  unsigned short* W1tailB = W1tailA + 4096;
  float* out  = (float*)d_out;

  prep_kernel<<<1120, 256, 0, stream>>>(q1W1, q2W1, q1W2, q2W2,
      W2bfA, W2bfB, W2TbfA, W2TbfB, W1TbfA, W1TbfB, W1tailA, W1tailB);

  fused_kernel<<<512, 512, 0, stream>>>(obs, a0,
      q1b1, q1b2, q1W3, q1b3,
      q2b1, q2b2, q2W3, q2b3,
      W2bfA, W2bfB, W2TbfA, W2TbfB, W1TbfA, W1TbfB, W1tailA, W1tailB,
      out);
}

// Round 9
// 461.023 us; speedup vs baseline: 1.2947x; 1.2947x over previous
//
#include <hip/hip_runtime.h>
#include <math.h>

#define LR 0.05f

typedef __attribute__((ext_vector_type(8))) short short8;
typedef __attribute__((ext_vector_type(4))) float f32x4;

#define MFMA16(a, b, c) __builtin_amdgcn_mfma_f32_16x16x32_bf16(a, b, c, 0, 0, 0)

__device__ __forceinline__ unsigned short f2bf(float v) {
  unsigned int u = __float_as_uint(v);
  u += 0x7fffu + ((u >> 16) & 1u);
  return (unsigned short)(u >> 16);
}

__device__ __forceinline__ void ce2(float& a, float& b, bool asc) {
  float lo = fminf(a, b), hi = fmaxf(a, b);
  a = asc ? lo : hi; b = asc ? hi : lo;
}

__device__ __forceinline__ void shufstage(float* v, int ebase, int j, int k) {
  int lm = j >> 2;
  bool amLow = ((ebase & j) == 0);
  bool asc = ((ebase & k) == 0);
  bool keepMin = (amLow == asc);
  #pragma unroll
  for (int m = 0; m < 4; ++m) {
    float pv = __shfl_xor(v[m], lm);
    v[m] = keepMin ? fminf(v[m], pv) : fmaxf(v[m], pv);
  }
}

__device__ __forceinline__ void smallstages(float* v, int ebase, int k) {
  if (k >= 4) {
    bool asc = ((ebase & k) == 0);
    ce2(v[0], v[2], asc); ce2(v[1], v[3], asc);
  }
  bool a01 = (((ebase + 0) & k) == 0);
  bool a23 = (((ebase + 2) & k) == 0);
  ce2(v[0], v[1], a01); ce2(v[2], v[3], a23);
}

// single-barrier LDS stage: ping-pong region removes read-before-overwrite hazard
__device__ __forceinline__ void ldsstage_p(float* v, int ebase, int j, int k, float* region) {
  #pragma unroll
  for (int m = 0; m < 4; ++m) region[ebase + m] = v[m];
  __syncthreads();
  bool amLow = ((ebase & j) == 0);
  bool asc = ((ebase & k) == 0);
  bool keepMin = (amLow == asc);
  #pragma unroll
  for (int m = 0; m < 4; ++m) {
    float pv = region[(ebase ^ j) + m];
    v[m] = keepMin ? fminf(v[m], pv) : fmaxf(v[m], pv);
  }
}

// ---------------- prep: build bf16 weight copies -----------------------------
__global__ __launch_bounds__(256) void prep_kernel(
    const float* __restrict__ W1a, const float* __restrict__ W1b,
    const float* __restrict__ W2a, const float* __restrict__ W2b,
    unsigned short* __restrict__ W2bfA, unsigned short* __restrict__ W2bfB,
    unsigned short* __restrict__ W2TbfA, unsigned short* __restrict__ W2TbfB,
    unsigned short* __restrict__ W1TbfA, unsigned short* __restrict__ W1TbfB,
    unsigned short* __restrict__ W1tailA, unsigned short* __restrict__ W1tailB)
{
  int i = blockIdx.x * 256 + threadIdx.x;
  if (i < 131072) {
    const float* W2 = (i >> 16) ? W2b : W2a;
    unsigned short* o = (i >> 16) ? W2bfB : W2bfA;
    int j = i & 65535;
    o[j] = f2bf(W2[j]);
  } else if (i < 262144) {
    int i2 = i - 131072;
    const float* W2 = (i2 >> 16) ? W2b : W2a;
    unsigned short* o = (i2 >> 16) ? W2TbfB : W2TbfA;
    int j = i2 & 65535;
    int n = j >> 8, k = j & 255;
    o[j] = f2bf(W2[k * 256 + n]);
  } else if (i < 278528) {
    int i2 = i - 262144;
    const float* W1 = (i2 >> 13) ? W1b : W1a;
    unsigned short* o = (i2 >> 13) ? W1TbfB : W1TbfA;
    int j = i2 & 8191;
    int n = j >> 5, k = j & 31;
    o[j] = (k < 23) ? f2bf(W1[k * 256 + n]) : (unsigned short)0;
  } else if (i < 286720) {
    int i2 = i - 278528;
    const float* W1 = (i2 >> 12) ? W1b : W1a;
    unsigned short* o = (i2 >> 12) ? W1tailB : W1tailA;
    int j = i2 & 4095;
    int d = j >> 8, tt = j & 255;
    o[j] = (d < 6) ? f2bf(W1[(17 + d) * 256 + tt]) : (unsigned short)0;
  }
}

// ---------------- fused: 5 x (score + SVGD) + epilogue, one block per batch --
// Register-tier design (R6-R8 evidence): unified VGPR+AGPR must be <=128/wave
// for the 4-waves/SIMD tier (4 blocks/CU, grid 1024 = one clean round).
// Accumulator peak capped at 16 AGPR everywhere:
//  - fwd h2pre: two 2-col-tile passes (acc[2][2])
//  - bwd: single selected-net dh2c buffer (buf0); 4 one-col-tile passes
//    computing P_a and P_b (8+8 regs), masked dh1 written to buf1 per pass
//    (h1b dead, no hazard, nothing held across a barrier)
//  - S: both Sa and Sb computed from the single dh1 buffer; per-row select.
__global__ __launch_bounds__(256) void fused_kernel(
    const float* __restrict__ obs, const float* __restrict__ a0,
    const float* __restrict__ b1a, const float* __restrict__ b2a,
    const float* __restrict__ W3a, const float* __restrict__ b3a,
    const float* __restrict__ b1b, const float* __restrict__ b2b,
    const float* __restrict__ W3b, const float* __restrict__ b3b,
    const unsigned short* __restrict__ W2bfA, const unsigned short* __restrict__ W2bfB,
    const unsigned short* __restrict__ W2TbfA, const unsigned short* __restrict__ W2TbfB,
    const unsigned short* __restrict__ W1TbfA, const unsigned short* __restrict__ W1TbfB,
    const unsigned short* __restrict__ W1tailA, const unsigned short* __restrict__ W1tailB,
    float* __restrict__ out)
{
  __shared__ __align__(16) unsigned short buf0[32][264];  // h1a -> dh2c; d2s aliases
  __shared__ __align__(16) unsigned short buf1[32][264];  // h1b -> dh1_m; sort ping-pong
  __shared__ __align__(16) unsigned short xsm[32][40];    // bf16 x (obs cols persist)
  __shared__ __align__(16) float upool[384];              // qpart[2][4][32] | redS[64][6]
  __shared__ float acur[32][6];
  __shared__ float Svv[32][6];
  __shared__ float XSsh[32];
  __shared__ float logps[32];
  __shared__ float asq[32];
  __shared__ int   selsh[32];
  __shared__ float medsh[2];

  float (*qpart)[4][32] = (float (*)[4][32])upool;
  float (*redS)[6] = (float (*)[6])upool;

  const int t = threadIdx.x;
  const int lane = t & 63, wv = t >> 6, quad = lane >> 4, l16 = lane & 15;
  const int b = blockIdx.x;
  const int base = b * 32;
  const int ctb = wv * 4;
  const long abase = (long)b * 192;

  float* d2s = (float*)&buf0[0][0];
  float* sortA = (float*)&buf1[0][0];
  float* sortB = sortA + 1024;

  // ---- init ----
  if (t < 192) { int r = t / 6, d = t - r * 6; acur[r][d] = a0[abase + t]; }
  if (t < 32) {
    float s = 0.f;
    #pragma unroll
    for (int d = 0; d < 6; ++d) { float x0 = a0[abase + t * 6 + d]; s += x0 * x0; }
    asq[t] = s; logps[t] = 0.f;
  }
  for (int idx = t; idx < 32 * 40; idx += 256) {
    int r = idx / 40, k = idx - r * 40;
    float v = 0.f;
    if (k < 17) v = obs[(base + r) * 17 + k];
    else if (k < 23) v = a0[abase + r * 6 + (k - 17)];
    xsm[r][k] = f2bf(v);
  }
  __syncthreads();

  #pragma unroll 1
  for (int s = 0; s < 5; ++s) {
    if (s > 0) {
      if (t < 192) { int r = t / 6, d = t - r * 6; xsm[r][17 + d] = f2bf(acur[r][d]); }
      __syncthreads();
    }

    // ================= score =================
    unsigned int m1a_bits = 0, m1b_bits = 0, m2a_bits = 0, m2b_bits = 0;

    #pragma unroll 1
    for (int net = 0; net < 2; ++net) {
      const unsigned short* W1T = net ? W1TbfB : W1TbfA;
      const unsigned short* W2T = net ? W2TbfB : W2TbfA;
      const float* b1 = net ? b1b : b1a;
      const float* b2 = net ? b2b : b2a;
      const float* W3 = net ? W3b : W3a;
      unsigned short (*hbuf)[264] = net ? buf1 : buf0;

      // h1 = relu(x @ W1 + b1); lane records its own mask bits (C-layout)
      unsigned int m1 = 0;
      {
        short8 ax0 = *(const short8*)&xsm[l16][quad * 8];
        short8 ax1 = *(const short8*)&xsm[16 + l16][quad * 8];
        #pragma unroll
        for (int c = 0; c < 4; ++c) {
          int col = (ctb + c) * 16 + l16;
          short8 bw = *(const short8*)&W1T[col * 32 + quad * 8];
          f32x4 z = {0.f, 0.f, 0.f, 0.f};
          f32x4 h0 = MFMA16(ax0, bw, z);
          f32x4 h1v = MFMA16(ax1, bw, z);
          float b1v = b1[col];
          #pragma unroll
          for (int g = 0; g < 4; ++g) {
            float v0 = h0[g] + b1v;
            float v1 = h1v[g] + b1v;
            if (v0 > 0.f) m1 |= 1u << ((0 * 4 + c) * 4 + g);
            if (v1 > 0.f) m1 |= 1u << ((1 * 4 + c) * 4 + g);
            hbuf[quad * 4 + g][col] = (v0 > 0.f) ? f2bf(v0) : (unsigned short)0;
            hbuf[16 + quad * 4 + g][col] = (v1 > 0.f) ? f2bf(v1) : (unsigned short)0;
          }
        }
      }
      if (net) m1b_bits = m1; else m1a_bits = m1;
      __syncthreads();

      // h2pre = h1 @ W2 — two 2-col-tile passes (acc peak 16 regs)
      float pq[2][4] = {{0.f, 0.f, 0.f, 0.f}, {0.f, 0.f, 0.f, 0.f}};
      unsigned int m2 = 0;
      #pragma unroll 1
      for (int hf = 0; hf < 2; ++hf) {
        f32x4 acc[2][2];
        acc[0][0] = acc[0][1] = acc[1][0] = acc[1][1] = (f32x4){0.f, 0.f, 0.f, 0.f};
        #pragma unroll 2
        for (int k = 0; k < 8; ++k) {
          short8 a0f = *(const short8*)&hbuf[l16][k * 32 + quad * 8];
          short8 a1f = *(const short8*)&hbuf[16 + l16][k * 32 + quad * 8];
          #pragma unroll
          for (int c = 0; c < 2; ++c) {
            int col = (ctb + hf * 2 + c) * 16 + l16;
            short8 bw = *(const short8*)&W2T[col * 256 + k * 32 + quad * 8];
            acc[0][c] = MFMA16(a0f, bw, acc[0][c]);
            acc[1][c] = MFMA16(a1f, bw, acc[1][c]);
          }
        }
        #pragma unroll
        for (int rt = 0; rt < 2; ++rt)
          #pragma unroll
          for (int c = 0; c < 2; ++c) {
            int cc = hf * 2 + c;
            int col = (ctb + cc) * 16 + l16;
            float b2v = b2[col], w3v = W3[col];
            #pragma unroll
            for (int g = 0; g < 4; ++g) {
              float v = acc[rt][c][g] + b2v;
              if (v > 0.f) {
                m2 |= 1u << ((rt * 4 + cc) * 4 + g);
                pq[rt][g] += v * w3v;
              }
            }
          }
      }
      if (net) m2b_bits = m2; else m2a_bits = m2;
      #pragma unroll
      for (int off = 8; off; off >>= 1) {
        #pragma unroll
        for (int rt = 0; rt < 2; ++rt)
          #pragma unroll
          for (int g = 0; g < 4; ++g)
            pq[rt][g] += __shfl_xor(pq[rt][g], off, 16);
      }
      if (l16 == 0) {
        #pragma unroll
        for (int rt = 0; rt < 2; ++rt)
          #pragma unroll
          for (int g = 0; g < 4; ++g)
            qpart[net][wv][rt * 16 + quad * 4 + g] = pq[rt][g];
      }
      __syncthreads();
    }

    // q assembly + min-selection
    if (t < 32) {
      float qa = b3a[0], qb = b3b[0];
      #pragma unroll
      for (int w = 0; w < 4; ++w) { qa += qpart[0][w][t]; qb += qpart[1][w][t]; }
      selsh[t] = (qa <= qb) ? 0 : 1;
    }
    __syncthreads();

    // dh2c: single buffer, selected net only (other net's entries were zero)
    #pragma unroll
    for (int rt = 0; rt < 2; ++rt)
      #pragma unroll
      for (int c = 0; c < 4; ++c) {
        int col = (ctb + c) * 16 + l16;
        unsigned short w3abf = f2bf(W3a[col]);
        unsigned short w3bbf = f2bf(W3b[col]);
        #pragma unroll
        for (int g = 0; g < 4; ++g) {
          int row = rt * 16 + quad * 4 + g;
          int sl = selsh[row];
          int bit = (rt * 4 + c) * 4 + g;
          unsigned int mb = sl ? m2b_bits : m2a_bits;
          unsigned short wv3 = sl ? w3bbf : w3abf;
          buf0[row][col] = ((mb >> bit) & 1) ? wv3 : (unsigned short)0;
        }
      }
    __syncthreads();

    // bwd: 4 one-col-tile passes; P_a, P_b (8+8 accum regs); masked dh1 -> buf1
    #pragma unroll 1
    for (int p = 0; p < 4; ++p) {
      int col = (ctb + p) * 16 + l16;
      f32x4 ba[2], bb[2];
      ba[0] = ba[1] = bb[0] = bb[1] = (f32x4){0.f, 0.f, 0.f, 0.f};
      #pragma unroll 2
      for (int k = 0; k < 8; ++k) {
        short8 bwA = *(const short8*)&W2bfA[col * 256 + k * 32 + quad * 8];
        short8 bwB = *(const short8*)&W2bfB[col * 256 + k * 32 + quad * 8];
        short8 a0d = *(const short8*)&buf0[l16][k * 32 + quad * 8];
        short8 a1d = *(const short8*)&buf0[16 + l16][k * 32 + quad * 8];
        ba[0] = MFMA16(a0d, bwA, ba[0]);
        bb[0] = MFMA16(a0d, bwB, bb[0]);
        ba[1] = MFMA16(a1d, bwA, ba[1]);
        bb[1] = MFMA16(a1d, bwB, bb[1]);
      }
      #pragma unroll
      for (int rt = 0; rt < 2; ++rt)
        #pragma unroll
        for (int g = 0; g < 4; ++g) {
          int row = rt * 16 + quad * 4 + g;
          int sl = selsh[row];
          float val = sl ? bb[rt][g] : ba[rt][g];
          unsigned int mb = sl ? m1b_bits : m1a_bits;
          int bit = (rt * 4 + p) * 4 + g;
          buf1[row][col] = ((mb >> bit) & 1) ? f2bf(val) : (unsigned short)0;
        }
    }
    __syncthreads();

    // S: both nets from the single dh1 buffer; per-row select happens at combine
    {
      int net = wv >> 1, rt = wv & 1;
      const unsigned short* Wt = net ? W1tailB : W1tailA;
      f32x4 sacc = {0.f, 0.f, 0.f, 0.f};
      #pragma unroll 2
      for (int k = 0; k < 8; ++k) {
        short8 a = *(const short8*)&buf1[rt * 16 + l16][k * 32 + quad * 8];
        short8 bb2 = *(const short8*)&Wt[l16 * 256 + k * 32 + quad * 8];
        sacc = MFMA16(a, bb2, sacc);
      }
      if (l16 < 6) {
        #pragma unroll
        for (int g = 0; g < 4; ++g)
          redS[net * 32 + rt * 16 + quad * 4 + g][l16] = sacc[g];
      }
    }
    __syncthreads();

    // ================= SVGD (in-block) =================
    if (t < 192) { int r = t / 6, d = t - r * 6; Svv[r][d] = redS[selsh[r] * 32 + r][d]; }
    for (int idx = t; idx < 1024; idx += 256) {
      int i = idx >> 5, j = idx & 31;
      float sd = 0.f;
      #pragma unroll
      for (int d = 0; d < 6; ++d) { float df = acur[i][d] - acur[j][d]; sd += df * df; }
      d2s[idx] = sd;
    }
    __syncthreads();
    if (t < 32) {
      float sx = 0.f;
      #pragma unroll
      for (int d = 0; d < 6; ++d) sx += acur[t][d] * Svv[t][d];
      XSsh[t] = sx;
    }

    // register/shuffle bitonic sort of 1024 dist^2 (exact median)
    const int ebase = wv * 256 + (t & 63) * 4;
    float v[4];
    #pragma unroll
    for (int m = 0; m < 4; ++m) v[m] = d2s[ebase + m];
    for (int k = 2; k <= 256; k <<= 1) {
      for (int j = k >> 1; j >= 4; j >>= 1) shufstage(v, ebase, j, k);
      smallstages(v, ebase, k);
    }
    ldsstage_p(v, ebase, 256, 512, sortA);
    for (int j = 128; j >= 4; j >>= 1) shufstage(v, ebase, j, 512);
    smallstages(v, ebase, 512);
    ldsstage_p(v, ebase, 512, 1024, sortB);
    ldsstage_p(v, ebase, 256, 1024, sortA);
    for (int j = 128; j >= 4; j >>= 1) shufstage(v, ebase, j, 1024);
    smallstages(v, ebase, 1024);

    #pragma unroll
    for (int m = 0; m < 4; ++m) {
      int e = ebase + m;
      if (e == 511) medsh[0] = v[m];
      if (e == 512) medsh[1] = v[m];
    }
    __syncthreads();
    float med = 0.5f * (medsh[0] + medsh[1]);
    float g = 1.0f / (2.0f * (med / logf(33.0f)) + 1e-8f);

    // K row-sums
    const int i = t >> 3, l = t & 7;
    float ks0=0,ks1=0,ks2=0,ks3=0,ks4=0,ks5=0;
    float kx0=0,kx1=0,kx2=0,kx3=0,kx4=0,kx5=0;
    float krow=0.f, kd2=0.f, kxs=0.f;
    #pragma unroll
    for (int jj = 0; jj < 4; ++jj) {
      int j = l + 8 * jj;
      float dv = d2s[i * 32 + j];
      float kv = expf(-g * dv);
      krow += kv; kd2 += kv * dv; kxs += kv * XSsh[j];
      ks0 += kv * Svv[j][0]; kx0 += kv * acur[j][0];
      ks1 += kv * Svv[j][1]; kx1 += kv * acur[j][1];
      ks2 += kv * Svv[j][2]; kx2 += kv * acur[j][2];
      ks3 += kv * Svv[j][3]; kx3 += kv * acur[j][3];
      ks4 += kv * Svv[j][4]; kx4 += kv * acur[j][4];
      ks5 += kv * Svv[j][5]; kx5 += kv * acur[j][5];
    }
    #pragma unroll
    for (int off = 4; off > 0; off >>= 1) {
      krow += __shfl_down(krow, off, 8);
      kd2  += __shfl_down(kd2,  off, 8);
      kxs  += __shfl_down(kxs,  off, 8);
      ks0 += __shfl_down(ks0, off, 8); kx0 += __shfl_down(kx0, off, 8);
      ks1 += __shfl_down(ks1, off, 8); kx1 += __shfl_down(kx1, off, 8);
      ks2 += __shfl_down(ks2, off, 8); kx2 += __shfl_down(kx2, off, 8);
      ks3 += __shfl_down(ks3, off, 8); kx3 += __shfl_down(kx3, off, 8);
      ks4 += __shfl_down(ks4, off, 8); kx4 += __shfl_down(kx4, off, 8);
      ks5 += __shfl_down(ks5, off, 8); kx5 += __shfl_down(kx5, off, 8);
    }
    float an0=0,an1=0,an2=0,an3=0,an4=0,an5=0, lpnew=0;
    if (l == 0) {
      const float inv_n = 1.0f / 32.0f;
      float t1sum = 0.f, p;
      p = (ks0 + 2.f*g*(acur[i][0]*krow - kx0)) * inv_n; an0 = acur[i][0] + LR * p; t1sum += acur[i][0] * ks0;
      p = (ks1 + 2.f*g*(acur[i][1]*krow - kx1)) * inv_n; an1 = acur[i][1] + LR * p; t1sum += acur[i][1] * ks1;
      p = (ks2 + 2.f*g*(acur[i][2]*krow - kx2)) * inv_n; an2 = acur[i][2] + LR * p; t1sum += acur[i][2] * ks2;
      p = (ks3 + 2.f*g*(acur[i][3]*krow - kx3)) * inv_n; an3 = acur[i][3] + LR * p; t1sum += acur[i][3] * ks3;
      p = (ks4 + 2.f*g*(acur[i][4]*krow - kx4)) * inv_n; an4 = acur[i][4] + LR * p; t1sum += acur[i][4] * ks4;
      p = (ks5 + 2.f*g*(acur[i][5]*krow - kx5)) * inv_n; an5 = acur[i][5] + LR * p; t1sum += acur[i][5] * ks5;
      float term1 = (-2.f * g / 31.f) * (t1sum - kxs);
      float term2 = (-2.f * g / 31.f) * (2.f * g * kd2 - 6.f * (krow - 1.f));
      lpnew = logps[i] - LR * (term1 + term2);
    }
    __syncthreads();
    if (l == 0) {
      acur[i][0] = an0; acur[i][1] = an1; acur[i][2] = an2;
      acur[i][3] = an3; acur[i][4] = an4; acur[i][5] = an5;
      logps[i] = lpnew;
    }
    __syncthreads();
  }

  // ================= epilogue =================
  if (t < 192) { int r = t / 6, d = t - r * 6; out[abase + t] = tanhf(acur[r][d]); }
  if (t < 32) {
    float st = 0.f;
    #pragma unroll
    for (int d = 0; d < 6; ++d) {
      float x = acur[t][d];
      float z = -2.f * x;
      float sp = fmaxf(z, 0.f) + log1pf(expf(-fabsf(z)));
      st += 2.f * (0.69314718056f - x - sp);
    }
    float lpn = -3.0f * logf(1.88495559215f) - (0.5f / 0.3f) * asq[t];
    XSsh[t] = lpn + logps[t] - st;
  }
  __syncthreads();
  if (t == 0) {
    float s = 0.f;
    #pragma unroll
    for (int n = 0; n < 32; ++n) s += XSsh[n];
    out[196608 + b] = s * (1.0f / 32.0f);
  }
}

extern "C" void kernel_launch(void* const* d_in, const int* in_sizes, int n_in,
                              void* d_out, int out_size, void* d_ws, size_t ws_size,
                              hipStream_t stream) {
  const float* obs  = (const float*)d_in[0];
  const float* a0   = (const float*)d_in[1];
  const float* q1W1 = (const float*)d_in[2];
  const float* q1b1 = (const float*)d_in[3];
  const float* q1W2 = (const float*)d_in[4];
  const float* q1b2 = (const float*)d_in[5];
  const float* q1W3 = (const float*)d_in[6];
  const float* q1b3 = (const float*)d_in[7];
  const float* q2W1 = (const float*)d_in[8];
  const float* q2b1 = (const float*)d_in[9];
  const float* q2W2 = (const float*)d_in[10];
  const float* q2b2 = (const float*)d_in[11];
  const float* q2W3 = (const float*)d_in[12];
  const float* q2b3 = (const float*)d_in[13];

  unsigned short* wsu = (unsigned short*)d_ws;
  unsigned short* W2bfA  = wsu;
  unsigned short* W2bfB  = W2bfA + 65536;
  unsigned short* W2TbfA = W2bfB + 65536;
  unsigned short* W2TbfB = W2TbfA + 65536;
  unsigned short* W1TbfA = W2TbfB + 65536;
  unsigned short* W1TbfB = W1TbfA + 8192;
  unsigned short* W1tailA = W1TbfB + 8192;
  unsigned short* W1tailB = W1tailA + 4096;
  float* out  = (float*)d_out;

  prep_kernel<<<1120, 256, 0, stream>>>(q1W1, q2W1, q1W2, q2W2,
      W2bfA, W2bfB, W2TbfA, W2TbfB, W1TbfA, W1TbfB, W1tailA, W1tailB);

  fused_kernel<<<1024, 256, 0, stream>>>(obs, a0,
      q1b1, q1b2, q1W3, q1b3,
      q2b1, q2b2, q2W3, q2b3,
      W2bfA, W2bfB, W2TbfA, W2TbfB, W1TbfA, W1TbfB, W1tailA, W1tailB,
      out);
}